// Round 2
// baseline (356.203 us; speedup 1.0000x reference)
//
#include <hip/hip_runtime.h>
#include <math.h>

// CapsuleRouting: u (8,144,16,16,12,12) f32, a (8,144,12,12) f32
// out: v (8,16,16,144) f32  ++  a_out (8,16,144) f32
//
// r_i = a/C + agreement(u, V_i), V_i = sum_{t<i} v_t  (agreement linear in v)
// => never materialize r; one streaming pass over u per iteration.
// Iter 0: softmax of a constant over C => uniform 1/16 => pure float4 streaming sum.
// Iters 1,2: single-exp no-max softmax via LDS (logits are O(10), fp32-safe),
// next-B loads double-buffered across the barrier.
//
// This version: cross-chunk reduction via PARTIAL-SUM STORES (plain stores)
// instead of 5.3M atomicAdds per pass; reduction folded into q. Legacy atomic
// path retained as runtime fallback if ws_size is too small.

#define NB 8
#define BDIM 144
#define CDIM 16
#define PDIM 16
#define SDIM 144
#define PT 16
#define BC 8                 // B per chunk
#define NPT (SDIM / PT)      // 9
#define NBC (BDIM / BC)      // 18
#define USTRIDE (CDIM * PDIM * SDIM)      // 36864 floats between consecutive B
#define VELEMS (NB * CDIM * PDIM * SDIM)  // 294912
#define AELEMS (NB * CDIM * SDIM)         // 18432

// ---------------- partial-store path ----------------

// iter 0: s = (1/C) * sum_B u  -- pure streaming, float4, per-chunk partials.
__global__ __launch_bounds__(256) void s0_kernel(const float* __restrict__ u,
                                                 float* __restrict__ part) {
  const int o = blockIdx.x * 256 + threadIdx.x;  // [0, 73728): (b,c,p,pos/4)
  const int chunk = blockIdx.y;
  const int q4 = o % 36;
  const int t1 = o / 36;
  const int p = t1 & 15;
  const int t2 = t1 >> 4;
  const int c = t2 & 15;
  const int b = t2 >> 4;

  const float4* ub = (const float4*)(u +
      ((size_t)((b * BDIM + chunk * BC) * CDIM + c) * PDIM + p) * SDIM) + q4;
  float sx = 0.f, sy = 0.f, sz = 0.f, sw = 0.f;
#pragma unroll
  for (int j = 0; j < BC; ++j) {
    const float4 v = ub[(size_t)j * (USTRIDE / 4)];
    sx += v.x; sy += v.y; sz += v.z; sw += v.w;
  }
  const float sc = 1.0f / CDIM;
  float4* sp = (float4*)(part + (size_t)chunk * VELEMS +
                         ((size_t)((b * CDIM + c) * PDIM + p)) * SDIM) + q4;
  *sp = make_float4(sx * sc, sy * sc, sz * sc, sw * sc);
}

// iters 1,2: softmax-weighted sum over the B chunk, partial per chunk.
__global__ __launch_bounds__(256) void sP_kernel(const float* __restrict__ u,
                                                 const float* __restrict__ a,
                                                 const float* __restrict__ V,
                                                 float* __restrict__ part) {
  __shared__ float Vt[CDIM][PDIM][PT + 1];  // padded: 4-way -> 2-way (free)
  __shared__ float ebuf[2][CDIM][PT + 1];
  __shared__ float atile[BC][PT];

  const int tid = threadIdx.x;
  const int pos = tid & 15;  // fast -> coalesced (64B runs per 16 lanes)
  const int c = tid >> 4;
  const int b = blockIdx.z;
  const int posg = blockIdx.y * PT + pos;
  const int B0 = blockIdx.x * BC;

  const float* ubase =
      u + ((size_t)((b * BDIM + B0) * CDIM + c) * PDIM) * SDIM + posg;

  // stage V tile and a tile
  {
    const int vb = ((b * CDIM + c) * PDIM) * SDIM + posg;
#pragma unroll
    for (int p = 0; p < PDIM; ++p) Vt[c][p][pos] = V[vb + p * SDIM];
    if (tid < BC * PT) {
      const int j = tid >> 4;
      atile[j][pos] =
          a[(b * BDIM + B0 + j) * SDIM + blockIdx.y * PT + pos] * (1.0f / CDIM);
    }
  }
  __syncthreads();

  float sacc[PDIM];
#pragma unroll
  for (int p = 0; p < PDIM; ++p) sacc[p] = 0.f;

  float uvbuf[2][PDIM];
#pragma unroll
  for (int p = 0; p < PDIM; ++p) uvbuf[0][p] = ubase[p * SDIM];  // prologue j=0

#pragma unroll
  for (int j = 0; j < BC; ++j) {
    float* uv = uvbuf[j & 1];
    float* uvn = uvbuf[(j + 1) & 1];
    if (j + 1 < BC) {  // issue next-B loads BEFORE the barrier (overlap stall)
      const float* ub = ubase + (size_t)(j + 1) * USTRIDE;
#pragma unroll
      for (int p = 0; p < PDIM; ++p) uvn[p] = ub[p * SDIM];
    }
    float dot = 0.f;
#pragma unroll
    for (int p = 0; p < PDIM; ++p) dot += uv[p] * Vt[c][p][pos];
    const float e = __expf(atile[j][pos] + dot);  // no-max softmax: |logit|~O(10)
    ebuf[j & 1][c][pos] = e;
    __syncthreads();
    float sum = 0.f;
#pragma unroll
    for (int c2 = 0; c2 < CDIM; ++c2) sum += ebuf[j & 1][c2][pos];
    const float w = e * __builtin_amdgcn_rcpf(sum);
#pragma unroll
    for (int p = 0; p < PDIM; ++p) sacc[p] += w * uv[p];
    // WAR on ebuf[j&1] is covered by barrier j+1 (ping-pong)
  }

  float* sp = part + (size_t)blockIdx.x * VELEMS +
              ((b * CDIM + c) * PDIM) * SDIM + posg;
#pragma unroll
  for (int p = 0; p < PDIM; ++p) sp[p * SDIM] = sacc[p];  // plain stores
}

// reduce NBC partials, squash, update V / write outputs.
__global__ __launch_bounds__(256) void qP_kernel(const float* __restrict__ part,
                                                 float* __restrict__ V,
                                                 float* __restrict__ out_v,
                                                 float* __restrict__ out_a,
                                                 int iter) {
  const int gid = blockIdx.x * 256 + threadIdx.x;
  const int b = gid / (CDIM * SDIM);
  const int rem = gid - b * (CDIM * SDIM);
  const int c = rem / SDIM;
  const int posg = rem - c * SDIM;
  const int base = ((b * CDIM + c) * PDIM) * SDIM + posg;

  float sv[PDIM];
#pragma unroll
  for (int p = 0; p < PDIM; ++p) sv[p] = 0.f;
#pragma unroll
  for (int k = 0; k < NBC; ++k) {
    const float* sp = part + (size_t)k * VELEMS + base;
#pragma unroll
    for (int p = 0; p < PDIM; ++p) sv[p] += sp[p * SDIM];
  }
  float sn = 0.f;
#pragma unroll
  for (int p = 0; p < PDIM; ++p) sn += sv[p] * sv[p];
  const float scale = sn / (1.0f + sn) * rsqrtf(sn);

  if (iter == 0) {
#pragma unroll
    for (int p = 0; p < PDIM; ++p) V[base + p * SDIM] = sv[p] * scale;
  } else if (iter == 1) {
#pragma unroll
    for (int p = 0; p < PDIM; ++p) V[base + p * SDIM] += sv[p] * scale;
  } else {
    float vv = 0.f;
#pragma unroll
    for (int p = 0; p < PDIM; ++p) {
      const float v = sv[p] * scale;
      out_v[base + p * SDIM] = v;
      vv += v * v;
    }
    out_a[gid] = sqrtf(vv);
  }
}

// ---------------- legacy atomic path (fallback, harness-verified) ----------------

__global__ __launch_bounds__(256) void s_kernel(const float* __restrict__ u,
                                                const float* __restrict__ a,
                                                const float* __restrict__ V,
                                                float* __restrict__ s,
                                                int iter) {
  __shared__ float Vt[CDIM][PDIM][PT];
  __shared__ float ebuf[2][CDIM][PT + 1];
  __shared__ float atile[BC][PT];

  const int tid = threadIdx.x;
  const int pos = tid & 15;
  const int c = tid >> 4;
  const int b = blockIdx.z;
  const int posg = blockIdx.y * PT + pos;
  const int B0 = blockIdx.x * BC;

  const float* ubase =
      u + ((size_t)((b * BDIM + B0) * CDIM + c) * PDIM) * SDIM + posg;

  float sacc[PDIM];
#pragma unroll
  for (int p = 0; p < PDIM; ++p) sacc[p] = 0.f;

  if (iter == 0) {
#pragma unroll 2
    for (int j = 0; j < BC; ++j) {
      const float* ub = ubase + (size_t)j * USTRIDE;
#pragma unroll
      for (int p = 0; p < PDIM; ++p) sacc[p] += ub[p * SDIM];
    }
    const int sb = ((b * CDIM + c) * PDIM) * SDIM + posg;
#pragma unroll
    for (int p = 0; p < PDIM; ++p)
      atomicAdd(&s[sb + p * SDIM], sacc[p] * (1.0f / CDIM));
    return;
  }

  {
    const int vb = ((b * CDIM + c) * PDIM) * SDIM + posg;
#pragma unroll
    for (int p = 0; p < PDIM; ++p) Vt[c][p][pos] = V[vb + p * SDIM];
    if (tid < BC * PT) {
      const int j = tid >> 4;
      atile[j][pos] =
          a[(b * BDIM + B0 + j) * SDIM + blockIdx.y * PT + pos] * (1.0f / CDIM);
    }
  }
  __syncthreads();

  float uvbuf[2][PDIM];
#pragma unroll
  for (int p = 0; p < PDIM; ++p) uvbuf[0][p] = ubase[p * SDIM];

#pragma unroll
  for (int j = 0; j < BC; ++j) {
    float* uv = uvbuf[j & 1];
    float* uvn = uvbuf[(j + 1) & 1];
    if (j + 1 < BC) {
      const float* ub = ubase + (size_t)(j + 1) * USTRIDE;
#pragma unroll
      for (int p = 0; p < PDIM; ++p) uvn[p] = ub[p * SDIM];
    }
    float dot = 0.f;
#pragma unroll
    for (int p = 0; p < PDIM; ++p) dot += uv[p] * Vt[c][p][pos];
    const float e = __expf(atile[j][pos] + dot);
    ebuf[j & 1][c][pos] = e;
    __syncthreads();
    float sum = 0.f;
#pragma unroll
    for (int c2 = 0; c2 < CDIM; ++c2) sum += ebuf[j & 1][c2][pos];
    const float w = e * __builtin_amdgcn_rcpf(sum);
#pragma unroll
    for (int p = 0; p < PDIM; ++p) sacc[p] += w * uv[p];
  }

  const int sb = ((b * CDIM + c) * PDIM) * SDIM + posg;
#pragma unroll
  for (int p = 0; p < PDIM; ++p) atomicAdd(&s[sb + p * SDIM], sacc[p]);
}

__global__ __launch_bounds__(256) void q_kernel(float* __restrict__ s,
                                                float* __restrict__ V,
                                                float* __restrict__ out_v,
                                                float* __restrict__ out_a,
                                                int iter) {
  const int gid = blockIdx.x * 256 + threadIdx.x;
  const int b = gid / (CDIM * SDIM);
  const int rem = gid - b * (CDIM * SDIM);
  const int c = rem / SDIM;
  const int posg = rem - c * SDIM;
  const int base = ((b * CDIM + c) * PDIM) * SDIM + posg;

  float sv[PDIM];
  float sn = 0.f;
#pragma unroll
  for (int p = 0; p < PDIM; ++p) {
    const float x = s[base + p * SDIM];
    sv[p] = x;
    sn += x * x;
  }
  const float scale = sn / (1.0f + sn) * rsqrtf(sn);

  if (iter < 2) {
#pragma unroll
    for (int p = 0; p < PDIM; ++p) {
      V[base + p * SDIM] += sv[p] * scale;
      s[base + p * SDIM] = 0.f;
    }
  } else {
    float vv = 0.f;
#pragma unroll
    for (int p = 0; p < PDIM; ++p) {
      const float v = sv[p] * scale;
      out_v[base + p * SDIM] = v;
      vv += v * v;
    }
    out_a[gid] = sqrtf(vv);
  }
}

// ---------------- launch ----------------

extern "C" void kernel_launch(void* const* d_in, const int* in_sizes, int n_in,
                              void* d_out, int out_size, void* d_ws, size_t ws_size,
                              hipStream_t stream) {
  const float* u = (const float*)d_in[0];
  const float* a = (const float*)d_in[1];
  float* out_v = (float*)d_out;
  float* out_a = out_v + VELEMS;
  float* V = (float*)d_ws;

  const size_t needP = (size_t)(1 + NBC) * VELEMS * sizeof(float);  // ~22.4 MB
  if (ws_size >= needP) {
    // partial-store path: no atomics, no memset, iter0 fully vectorized
    float* part = V + VELEMS;
    const dim3 gS(NBC, NPT, NB);  // 18 x 9 x 8
    for (int it = 0; it < 3; ++it) {
      if (it == 0)
        s0_kernel<<<dim3(VELEMS / 4 / 256, NBC), 256, 0, stream>>>(u, part);
      else
        sP_kernel<<<gS, 256, 0, stream>>>(u, a, V, part);
      qP_kernel<<<AELEMS / 256, 256, 0, stream>>>(part, V, out_v, out_a, it);
    }
  } else {
    // legacy atomic path
    float* s = V + VELEMS;
    hipMemsetAsync(d_ws, 0, (size_t)2 * VELEMS * sizeof(float), stream);
    const dim3 gS(NBC, NPT, NB);
    for (int it = 0; it < 3; ++it) {
      s_kernel<<<gS, 256, 0, stream>>>(u, a, V, s, it);
      q_kernel<<<AELEMS / 256, 256, 0, stream>>>(s, V, out_v, out_a, it);
    }
  }
}